// Round 6
// baseline (2486.676 us; speedup 1.0000x reference)
//
#include <hip/hip_runtime.h>
#include <cstdint>

constexpr int Hh = 64, Wd = 64, Cc = 512;
constexpr int HW = 4096;
#define BN_EPS 1e-3f

typedef __attribute__((ext_vector_type(8))) short short8;
typedef __attribute__((ext_vector_type(4))) float f32x4;

__device__ __forceinline__ void gld16(const void* g, void* l) {
    __builtin_amdgcn_global_load_lds((const __attribute__((address_space(1))) void*)g,
                                     (__attribute__((address_space(3))) void*)l, 16, 0, 0);
}
__device__ __forceinline__ unsigned short bf_rne(float f) {
    uint32_t u = __float_as_uint(f);
    return (unsigned short)((u + 0x7fffu + ((u >> 16) & 1u)) >> 16);
}
// RNE split: f ~= hi + lo with hi = RNE_bf16(f), lo = RNE_bf16(f - hi).
// (used for weights + epilogue; x staging uses the fast perm-based trunc split)
__device__ __forceinline__ void split2(float f, unsigned short& hi, unsigned short& lo) {
    hi = bf_rne(f);
    float hf = __uint_as_float((uint32_t)hi << 16);
    lo = bf_rne(f - hf);
}
// short-index of logical [r][q*8] in a [128 rows][4 slots of 16B] plane,
// slot-swizzled: phys_slot = q ^ ((r>>1)&3)  -> conflict-free ds_read_b128
__device__ __forceinline__ int swz8(int r, int q) {
    return r * 32 + (((q ^ (r >> 1)) & 3) << 3);
}
__device__ __forceinline__ short8 msel(bool v, short8 a) {
    short m = v ? (short)-1 : (short)0;
    short8 mv = {m, m, m, m, m, m, m, m};
    return a & mv;
}

// ---------------------------------------------------------------------------
// W [tap][cin][cout] fp32 -> Wt_hi/lo [cout][tap*512+cin] bf16. grid (16,16,9)
// ---------------------------------------------------------------------------
__global__ __launch_bounds__(256)
void wsplit_k(const float* __restrict__ W, unsigned short* __restrict__ wh,
              unsigned short* __restrict__ wl)
{
    __shared__ float T[32][33];
    const int tap = blockIdx.z, ci0 = blockIdx.x * 32, co0 = blockIdx.y * 32;
    const int t = threadIdx.x;
    const int ci = t >> 5, co = t & 31;
    #pragma unroll
    for (int rep = 0; rep < 4; ++rep)
        T[ci + rep * 8][co] = W[(size_t)((tap * Cc) + ci0 + ci + rep * 8) * Cc + co0 + co];
    __syncthreads();
    const int co2 = t >> 5, ci2 = t & 31;
    #pragma unroll
    for (int rep = 0; rep < 4; ++rep) {
        float v = T[ci2][co2 + rep * 8];
        unsigned short h, l; split2(v, h, l);
        size_t addr = (size_t)(co0 + co2 + rep * 8) * 4608 + (size_t)tap * Cc + ci0 + ci2;
        wh[addr] = h; wl[addr] = l;
    }
}

// ---------------------------------------------------------------------------
// FUSED Q+K conv3x3 SAME + BN + ReLU, split-bf16 (3 MFMA products each).
// VALU-diet staging: tap-invariant clamped bases + masks (9x not 144x),
// const-offset loads (imm-folded), perm-based truncation split, unroll-4
// register ping-pong. A: double-buffered gld16, counted vmcnt(12).
// grid 2048 (1D, XCD-swizzled). Outputs transposed [b][c][n] hi/lo.
// ---------------------------------------------------------------------------
struct QkA { short QH[128][32]; short QL[128][32]; short KH[128][32]; short KL[128][32]; }; // 32 KB
struct QkB { short BH[128][32]; short BL[128][32]; };                                      // 16 KB
struct QkLds { QkA a[2]; QkB b; };                                                         // 80 KB

__global__ __launch_bounds__(256, 2)
void conv_qk_k(const float* __restrict__ x,
               const unsigned short* __restrict__ wqh, const unsigned short* __restrict__ wql,
               const unsigned short* __restrict__ wkh, const unsigned short* __restrict__ wkl,
               const float* __restrict__ bq_, const float* __restrict__ qg_,
               const float* __restrict__ qbt_, const float* __restrict__ qm_,
               const float* __restrict__ qv_,
               const float* __restrict__ bk_, const float* __restrict__ kg_,
               const float* __restrict__ kbt_, const float* __restrict__ km_,
               const float* __restrict__ kv_,
               unsigned short* __restrict__ q_h, unsigned short* __restrict__ q_l,
               unsigned short* __restrict__ k_h, unsigned short* __restrict__ k_l)
{
    __shared__ QkLds lds;
    const int t = threadIdx.x;
    const int wg = (blockIdx.x & 7) * 256 + (blockIdx.x >> 3);   // bijective XCD swizzle
    const int bcout = (wg & 3) * 128;
    const int m0    = ((wg >> 2) & 31) * 128;
    const int b     = wg >> 7;
    const int lane = t & 63, wave = t >> 6;
    const int wr = wave >> 1, wc = wave & 1;

    const int row0 = t >> 2;                      // 0..63
    const int slot = t & 3;                       // logical 16B slot (B staging)
    const int qlog = slot ^ ((t >> 3) & 3);       // pre-swizzled source slot (A gld16)

    const int m_r0 = m0 + row0, m_r1 = m_r0 + 64;
    const int h0 = m_r0 >> 6, w0 = m_r0 & 63;
    const int h1 = m_r1 >> 6, w1 = m_r1 & 63;
    const float* xb = x + (size_t)b * HW * Cc;

    // persistent per-lane weight row pointers (k advances linearly: s*32 shorts)
    const size_t ar0 = (size_t)(bcout + row0) * 4608 + qlog * 8;
    const size_t ar1 = (size_t)(bcout + row0 + 64) * 4608 + qlog * 8;
    const unsigned short* pQH0 = wqh + ar0; const unsigned short* pQH1 = wqh + ar1;
    const unsigned short* pQL0 = wql + ar0; const unsigned short* pQL1 = wql + ar1;
    const unsigned short* pKH0 = wkh + ar0; const unsigned short* pKH1 = wkh + ar1;
    const unsigned short* pKL0 = wkl + ar0; const unsigned short* pKL1 = wkl + ar1;

    const int dsb0 = swz8(row0, slot);            // static ds_write targets
    const int dsb1 = swz8(row0 + 64, slot);

    f32x4 accq[4][4] = {};
    f32x4 acck[4][4] = {};
    float4 XA[4], XB[4];

    struct Ctx { const float* p0; const float* p1; bool v0, v1; };
    auto mkctx = [&](int tap) {
        Ctx c;
        const int dy = tap / 3 - 1, dx = tap % 3 - 1;
        int hp = h0 + dy, wp = w0 + dx;
        c.v0 = ((unsigned)hp < 64u) & ((unsigned)wp < 64u);
        c.p0 = xb + ((size_t)(min(max(hp, 0), 63) * Wd + min(max(wp, 0), 63))) * Cc + slot * 8;
        hp = h1 + dy; wp = w1 + dx;
        c.v1 = ((unsigned)hp < 64u) & ((unsigned)wp < 64u);
        c.p1 = xb + ((size_t)(min(max(hp, 0), 63) * Wd + min(max(wp, 0), 63))) * Cc + slot * 8;
        return c;
    };
    auto xload = [&](const float* p0, const float* p1, int off, float4* X) {
        X[0] = *(const float4*)(p0 + off);
        X[1] = *(const float4*)(p0 + off + 4);
        X[2] = *(const float4*)(p1 + off);
        X[3] = *(const float4*)(p1 + off + 4);
    };
    auto issueA = [&](int sn, int buf) {   // 8 gld16; offsets fold to immediates
        const size_t o = (size_t)sn * 32;
        short* dA = (short*)&lds.a[buf];
        gld16(pQH0 + o, dA + t * 8);
        gld16(pQH1 + o, dA + t * 8 + 2048);
        gld16(pQL0 + o, dA + 4096 + t * 8);
        gld16(pQL1 + o, dA + 4096 + t * 8 + 2048);
        gld16(pKH0 + o, dA + 8192 + t * 8);
        gld16(pKH1 + o, dA + 8192 + t * 8 + 2048);
        gld16(pKL0 + o, dA + 12288 + t * 8);
        gld16(pKL1 + o, dA + 12288 + t * 8 + 2048);
    };
    // perm-based truncation split + mask + ds_write (hot path)
    auto stageB = [&](const float4* X, bool v0, bool v1) {
        uint32_t hi[4], lo[4];
        auto packrow = [&](const float4& A, const float4& Bq, uint32_t msk) {
            const uint32_t* a  = (const uint32_t*)&A;
            const uint32_t* bb = (const uint32_t*)&Bq;
            uint32_t f[8] = {a[0], a[1], a[2], a[3], bb[0], bb[1], bb[2], bb[3]};
            #pragma unroll
            for (int p2 = 0; p2 < 4; ++p2) {
                uint32_t f0 = f[2 * p2], f1 = f[2 * p2 + 1];
                hi[p2] = __builtin_amdgcn_perm(f1, f0, 0x07060302u) & msk;
                float d0 = __uint_as_float(f0) - __uint_as_float(f0 & 0xffff0000u);
                float d1 = __uint_as_float(f1) - __uint_as_float(f1 & 0xffff0000u);
                lo[p2] = __builtin_amdgcn_perm(__float_as_uint(d1), __float_as_uint(d0),
                                               0x07060302u) & msk;
            }
        };
        short* BH = (short*)lds.b.BH;
        short* BL = (short*)lds.b.BL;
        packrow(X[0], X[1], v0 ? 0xffffffffu : 0u);
        *(uint4*)(BH + dsb0) = *(uint4*)hi;
        *(uint4*)(BL + dsb0) = *(uint4*)lo;
        packrow(X[2], X[3], v1 ? 0xffffffffu : 0u);
        *(uint4*)(BH + dsb1) = *(uint4*)hi;
        *(uint4*)(BL + dsb1) = *(uint4*)lo;
    };
    auto compute = [&](int abuf) {
        QkA* ab = &lds.a[abuf];
        const int kq = lane >> 4;
        short8 ah[4], al[4];
        // ---- phase Q ----
        #pragma unroll
        for (int i = 0; i < 4; ++i) {
            const int r = wr * 64 + i * 16 + (lane & 15);
            ah[i] = *(const short8*)((const short*)ab->QH + swz8(r, kq));
            al[i] = *(const short8*)((const short*)ab->QL + swz8(r, kq));
        }
        __builtin_amdgcn_s_setprio(1);
        #pragma unroll
        for (int j = 0; j < 4; ++j) {
            const int r = wc * 64 + j * 16 + (lane & 15);
            short8 bh = *(const short8*)((const short*)lds.b.BH + swz8(r, kq));
            short8 bl = *(const short8*)((const short*)lds.b.BL + swz8(r, kq));
            #pragma unroll
            for (int i = 0; i < 4; ++i) {
                accq[i][j] = __builtin_amdgcn_mfma_f32_16x16x32_bf16(ah[i], bh, accq[i][j], 0, 0, 0);
                accq[i][j] = __builtin_amdgcn_mfma_f32_16x16x32_bf16(ah[i], bl, accq[i][j], 0, 0, 0);
                accq[i][j] = __builtin_amdgcn_mfma_f32_16x16x32_bf16(al[i], bh, accq[i][j], 0, 0, 0);
            }
        }
        __builtin_amdgcn_s_setprio(0);
        // ---- phase K ----
        #pragma unroll
        for (int i = 0; i < 4; ++i) {
            const int r = wr * 64 + i * 16 + (lane & 15);
            ah[i] = *(const short8*)((const short*)ab->KH + swz8(r, kq));
            al[i] = *(const short8*)((const short*)ab->KL + swz8(r, kq));
        }
        __builtin_amdgcn_s_setprio(1);
        #pragma unroll
        for (int j = 0; j < 4; ++j) {
            const int r = wc * 64 + j * 16 + (lane & 15);
            short8 bh = *(const short8*)((const short*)lds.b.BH + swz8(r, kq));
            short8 bl = *(const short8*)((const short*)lds.b.BL + swz8(r, kq));
            #pragma unroll
            for (int i = 0; i < 4; ++i) {
                acck[i][j] = __builtin_amdgcn_mfma_f32_16x16x32_bf16(ah[i], bh, acck[i][j], 0, 0, 0);
                acck[i][j] = __builtin_amdgcn_mfma_f32_16x16x32_bf16(ah[i], bl, acck[i][j], 0, 0, 0);
                acck[i][j] = __builtin_amdgcn_mfma_f32_16x16x32_bf16(al[i], bh, acck[i][j], 0, 0, 0);
            }
        }
        __builtin_amdgcn_s_setprio(0);
    };

    Ctx cur = mkctx(0);
    xload(cur.p0, cur.p1, 0, XA);
    issueA(0, 0);

    int s = 0;
    for (int tap = 0; tap < 9; ++tap) {
        Ctx nxt = (tap < 8) ? mkctx(tap + 1) : cur;
        for (int cc = 0; cc < 4; ++cc) {
            #pragma unroll
            for (int j = 0; j < 4; ++j) {
                const int ck = cc * 4 + j;
                const bool lastOfTap = (cc == 3) && (j == 3);
                // x for step s+1 (tap+1 step 0 at tap boundary); regs ping-pong by parity
                const float* lp0 = lastOfTap ? nxt.p0 : cur.p0;
                const float* lp1 = lastOfTap ? nxt.p1 : cur.p1;
                const int    off = lastOfTap ? 0 : (ck + 1) * 32;
                xload(lp0, lp1, off, (j & 1) ? XA : XB);
                issueA(s + 1, (j ^ 1) & 1);         // (s+1)&1 == (j+1)&1  (static)
                stageB((j & 1) ? XB : XA, cur.v0, cur.v1);
                __builtin_amdgcn_sched_barrier(0);
                asm volatile("s_waitcnt vmcnt(12) lgkmcnt(0)" ::: "memory");  // A(s) landed
                __builtin_amdgcn_sched_barrier(0);
                __builtin_amdgcn_s_barrier();
                compute(j & 1);                      // s&1 == j&1  (static)
                __builtin_amdgcn_s_barrier();
                ++s;
            }
        }
        cur = nxt;
    }
    // note: final iteration issues one harmless prefetch (s=144) that stays
    // within d_ws (weight planes are adjacent) and is never consumed.

    // epilogue: folded BN + ReLU for q and k; write transposed hi/lo planes
    #pragma unroll
    for (int i = 0; i < 4; ++i) {
        #pragma unroll
        for (int r = 0; r < 4; ++r) {
            const int co = bcout + wr * 64 + i * 16 + (lane >> 4) * 4 + r;
            const float scq = qg_[co] * rsqrtf(qv_[co] + BN_EPS);
            const float tbq = (bq_[co] - qm_[co]) * scq + qbt_[co];
            const float sck = kg_[co] * rsqrtf(kv_[co] + BN_EPS);
            const float tbk = (bk_[co] - km_[co]) * sck + kbt_[co];
            const size_t rowb = ((size_t)(b * Cc + co)) * HW;
            #pragma unroll
            for (int j = 0; j < 4; ++j) {
                const int n = m0 + wc * 64 + j * 16 + (lane & 15);
                const float yq = fmaxf(fmaf(accq[i][j][r], scq, tbq), 0.f);
                const float yk = fmaxf(fmaf(acck[i][j][r], sck, tbk), 0.f);
                unsigned short h, l;
                split2(yq, h, l); q_h[rowb + n] = h; q_l[rowb + n] = l;
                split2(yk, h, l); k_h[rowb + n] = h; k_l[rowb + n] = l;
            }
        }
    }
}

// ---------------------------------------------------------------------------
// V conv3x3 SAME + BN + ReLU, PLAIN bf16 (1 MFMA product; wv_h/x are RNE).
// Stores v [b][n][c] bf16 via LDS transpose. grid 2048 (1D swizzled).
// ---------------------------------------------------------------------------
union VLds {
    struct { short A0[2][128][32]; short BH[128][32]; } s;  // 24 KB
    short T[128][136];                                      // 34 KB
};

__global__ __launch_bounds__(256, 4)
void conv_v_k(const float* __restrict__ x, const unsigned short* __restrict__ wvh,
              const float* __restrict__ bv_, const float* __restrict__ vg_,
              const float* __restrict__ vbt_, const float* __restrict__ vm_,
              const float* __restrict__ vv_,
              unsigned short* __restrict__ vout)
{
    __shared__ VLds lds;
    const int t = threadIdx.x;
    const int wg = (blockIdx.x & 7) * 256 + (blockIdx.x >> 3);
    const int bcout = (wg & 3) * 128;
    const int m0    = ((wg >> 2) & 31) * 128;
    const int b     = wg >> 7;
    const int lane = t & 63, wave = t >> 6;
    const int wr = wave >> 1, wc = wave & 1;

    const int row0 = t >> 2;
    const int slot = t & 3;
    const int qlog = slot ^ ((t >> 3) & 3);

    const int m_r0 = m0 + row0, m_r1 = m_r0 + 64;
    const int h0 = m_r0 >> 6, w0 = m_r0 & 63;
    const int h1 = m_r1 >> 6, w1 = m_r1 & 63;
    const float* xb = x + (size_t)b * HW * Cc;

    f32x4 acc[4][4] = {};
    float xc[16], xn[16];
    bool vc0, vc1, vn0, vn1;

    auto loadx = [&](int ks, float* xd, bool& v0, bool& v1) {
        const int tap = ks >> 4;
        const int kk  = ((ks & 15) << 5) + slot * 8;
        const int dy = tap / 3 - 1, dx = tap % 3 - 1;
        {
            const int hp = h0 + dy, wp = w0 + dx;
            v0 = ((unsigned)hp < 64u) & ((unsigned)wp < 64u);
            const int hc = min(max(hp, 0), 63), wcl = min(max(wp, 0), 63);
            const float* p = xb + ((size_t)(hc * Wd + wcl)) * Cc + kk;
            float4 u0 = *(const float4*)p;
            float4 u1 = *(const float4*)(p + 4);
            xd[0] = u0.x; xd[1] = u0.y; xd[2] = u0.z; xd[3] = u0.w;
            xd[4] = u1.x; xd[5] = u1.y; xd[6] = u1.z; xd[7] = u1.w;
        }
        {
            const int hp = h1 + dy, wp = w1 + dx;
            v1 = ((unsigned)hp < 64u) & ((unsigned)wp < 64u);
            const int hc = min(max(hp, 0), 63), wcl = min(max(wp, 0), 63);
            const float* p = xb + ((size_t)(hc * Wd + wcl)) * Cc + kk;
            float4 u0 = *(const float4*)p;
            float4 u1 = *(const float4*)(p + 4);
            xd[8]  = u0.x; xd[9]  = u0.y; xd[10] = u0.z; xd[11] = u0.w;
            xd[12] = u1.x; xd[13] = u1.y; xd[14] = u1.z; xd[15] = u1.w;
        }
    };
    auto issueA = [&](int ks, int buf) {   // 2 gld16
        const int tap = ks >> 4;
        const size_t kb = (size_t)tap * Cc + ((ks & 15) << 5) + qlog * 8;
        gld16(wvh + (size_t)(bcout + row0)      * 4608 + kb, (short*)lds.s.A0[buf] + t * 8);
        gld16(wvh + (size_t)(bcout + row0 + 64) * 4608 + kb, (short*)lds.s.A0[buf] + t * 8 + 2048);
    };
    auto writeB = [&]() {   // RNE round, mask, swizzled ds_write (hi only)
        short8 hv;
        #pragma unroll
        for (int q2 = 0; q2 < 8; ++q2) hv[q2] = (short)bf_rne(xc[q2]);
        *(short8*)((short*)lds.s.BH + swz8(row0, slot)) = msel(vc0, hv);
        #pragma unroll
        for (int q2 = 0; q2 < 8; ++q2) hv[q2] = (short)bf_rne(xc[8 + q2]);
        *(short8*)((short*)lds.s.BH + swz8(row0 + 64, slot)) = msel(vc1, hv);
    };
    auto compute = [&](int buf) {
        const int kq = lane >> 4;
        short8 ah[4];
        #pragma unroll
        for (int i = 0; i < 4; ++i)
            ah[i] = *(const short8*)((const short*)lds.s.A0[buf] + swz8(wr * 64 + i * 16 + (lane & 15), kq));
        __builtin_amdgcn_s_setprio(1);
        #pragma unroll
        for (int j = 0; j < 4; ++j) {
            short8 bh = *(const short8*)((const short*)lds.s.BH + swz8(wc * 64 + j * 16 + (lane & 15), kq));
            #pragma unroll
            for (int i = 0; i < 4; ++i)
                acc[i][j] = __builtin_amdgcn_mfma_f32_16x16x32_bf16(ah[i], bh, acc[i][j], 0, 0, 0);
        }
        __builtin_amdgcn_s_setprio(0);
    };

    loadx(0, xc, vc0, vc1);
    issueA(0, 0);

    for (int ks = 0; ks < 143; ++ks) {
        loadx(ks + 1, xn, vn0, vn1);      // 4 vmem
        issueA(ks + 1, (ks & 1) ^ 1);     // 2 gld16
        writeB();
        __builtin_amdgcn_sched_barrier(0);
        asm volatile("s_waitcnt vmcnt(6) lgkmcnt(0)" ::: "memory");  // A(ks) landed
        __builtin_amdgcn_sched_barrier(0);
        __builtin_amdgcn_s_barrier();
        compute(ks & 1);
        __builtin_amdgcn_s_barrier();
        #pragma unroll
        for (int q2 = 0; q2 < 16; ++q2) xc[q2] = xn[q2];
        vc0 = vn0; vc1 = vn1;
    }
    writeB();
    __builtin_amdgcn_sched_barrier(0);
    asm volatile("s_waitcnt vmcnt(0) lgkmcnt(0)" ::: "memory");
    __builtin_amdgcn_sched_barrier(0);
    __builtin_amdgcn_s_barrier();
    compute(1);

    // epilogue: BN+ReLU, transpose to [n][c] through LDS
    __syncthreads();
    #pragma unroll
    for (int i = 0; i < 4; ++i) {
        #pragma unroll
        for (int r = 0; r < 4; ++r) {
            const int cl = wr * 64 + i * 16 + (lane >> 4) * 4 + r;
            const int co = bcout + cl;
            const float sc = vg_[co] * rsqrtf(vv_[co] + BN_EPS);
            const float tb = (bv_[co] - vm_[co]) * sc + vbt_[co];
            #pragma unroll
            for (int j = 0; j < 4; ++j) {
                const int nl = wc * 64 + j * 16 + (lane & 15);
                const float y = fmaxf(fmaf(acc[i][j][r], sc, tb), 0.f);
                lds.T[nl][cl] = (short)bf_rne(y);
            }
        }
    }
    __syncthreads();
    #pragma unroll
    for (int rep = 0; rep < 4; ++rep) {
        const int nl = (t >> 3) + rep * 32;
        const int c0l = (t & 7) * 16;
        short8 v0 = *(const short8*)&lds.T[nl][c0l];
        short8 v1 = *(const short8*)&lds.T[nl][c0l + 8];
        const size_t base = ((size_t)(b * HW + m0 + nl)) * Cc + bcout + c0l;
        *(short8*)&vout[base] = v0;
        *(short8*)&vout[base + 8] = v1;
    }
}

// ---------------------------------------------------------------------------
// energy[b][c][d] = sum_n q_t[c][n] k_t[d][n], split-bf16, split-K=2.
// grid 512 (1D swizzled): z = b*2 + half -> e_a / e_b partials.
// ---------------------------------------------------------------------------
struct EBuf { short Ah[128][32]; short Al[128][32]; short Bh[128][32]; short Bl[128][32]; }; // 32 KB

__global__ __launch_bounds__(256, 2)
void energy_k(const unsigned short* __restrict__ qh, const unsigned short* __restrict__ ql,
              const unsigned short* __restrict__ kh, const unsigned short* __restrict__ kl,
              float* __restrict__ ea, float* __restrict__ eb)
{
    __shared__ EBuf ebuf[2];   // 64 KB
    const int t = threadIdx.x;
    const int wg = (blockIdx.x & 7) * 64 + (blockIdx.x >> 3);
    const int d0 = (wg & 3) * 128;
    const int c0 = ((wg >> 2) & 3) * 128;
    const int z  = wg >> 4;
    const int b  = z >> 1;
    const int nb0 = (z & 1) * 2048;
    float* __restrict__ eo = (z & 1) ? eb : ea;
    const int lane = t & 63, wave = t >> 6, wr = wave >> 1, wc = wave & 1;
    const int row0 = t >> 2;
    const int qlog = (t & 3) ^ ((t >> 3) & 3);

    const size_t qb = (size_t)b * Cc * HW;
    f32x4 acc[4][4] = {};

    auto issue = [&](int ks, EBuf* e8) {   // 8 gld16
        const size_t nb = nb0 + (size_t)ks * 32 + qlog * 8;
        gld16(qh + qb + (size_t)(c0 + row0)      * HW + nb, (short*)e8->Ah + t * 8);
        gld16(qh + qb + (size_t)(c0 + row0 + 64) * HW + nb, (short*)e8->Ah + t * 8 + 2048);
        gld16(ql + qb + (size_t)(c0 + row0)      * HW + nb, (short*)e8->Al + t * 8);
        gld16(ql + qb + (size_t)(c0 + row0 + 64) * HW + nb, (short*)e8->Al + t * 8 + 2048);
        gld16(kh + qb + (size_t)(d0 + row0)      * HW + nb, (short*)e8->Bh + t * 8);
        gld16(kh + qb + (size_t)(d0 + row0 + 64) * HW + nb, (short*)e8->Bh + t * 8 + 2048);
        gld16(kl + qb + (size_t)(d0 + row0)      * HW + nb, (short*)e8->Bl + t * 8);
        gld16(kl + qb + (size_t)(d0 + row0 + 64) * HW + nb, (short*)e8->Bl + t * 8 + 2048);
    };
    auto compute = [&](EBuf* e8) {
        short8 ah[4], al[4];
        const int kq = lane >> 4;
        #pragma unroll
        for (int i = 0; i < 4; ++i) {
            const int r = wr * 64 + i * 16 + (lane & 15);
            ah[i] = *(const short8*)((const short*)e8->Ah + swz8(r, kq));
            al[i] = *(const short8*)((const short*)e8->Al + swz8(r, kq));
        }
        __builtin_amdgcn_s_setprio(1);
        #pragma unroll
        for (int j = 0; j < 4; ++j) {
            const int r = wc * 64 + j * 16 + (lane & 15);
            short8 bh = *(const short8*)((const short*)e8->Bh + swz8(r, kq));
            short8 bl = *(const short8*)((const short*)e8->Bl + swz8(r, kq));
            #pragma unroll
            for (int i = 0; i < 4; ++i) {
                acc[i][j] = __builtin_amdgcn_mfma_f32_16x16x32_bf16(ah[i], bh, acc[i][j], 0, 0, 0);
                acc[i][j] = __builtin_amdgcn_mfma_f32_16x16x32_bf16(ah[i], bl, acc[i][j], 0, 0, 0);
                acc[i][j] = __builtin_amdgcn_mfma_f32_16x16x32_bf16(al[i], bh, acc[i][j], 0, 0, 0);
            }
        }
        __builtin_amdgcn_s_setprio(0);
    };

    issue(0, &ebuf[0]);
    for (int ks = 0; ks < 63; ++ks) {
        issue(ks + 1, &ebuf[(ks & 1) ^ 1]);
        __builtin_amdgcn_sched_barrier(0);
        asm volatile("s_waitcnt vmcnt(8)" ::: "memory");
        __builtin_amdgcn_sched_barrier(0);
        __builtin_amdgcn_s_barrier();
        compute(&ebuf[ks & 1]);
        __builtin_amdgcn_s_barrier();
    }
    __builtin_amdgcn_sched_barrier(0);
    asm volatile("s_waitcnt vmcnt(0)" ::: "memory");
    __builtin_amdgcn_sched_barrier(0);
    __builtin_amdgcn_s_barrier();
    compute(&ebuf[1]);

    #pragma unroll
    for (int i = 0; i < 4; ++i)
        #pragma unroll
        for (int r = 0; r < 4; ++r) {
            const int c = c0 + wr * 64 + i * 16 + (lane >> 4) * 4 + r;
            #pragma unroll
            for (int j = 0; j < 4; ++j) {
                const int d = d0 + wc * 64 + j * 16 + (lane & 15);
                eo[((size_t)(b * Cc) + c) * Cc + d] = acc[i][j][r];
            }
        }
}

// ---------------------------------------------------------------------------
// softmax rows (B*C = 8192), adds split-K partials, writes bf16 attn
// ---------------------------------------------------------------------------
__global__ __launch_bounds__(256)
void softmax_k(const float* __restrict__ ea, const float* __restrict__ eb,
               unsigned short* __restrict__ attn)
{
    __shared__ float red[256];
    const int r = blockIdx.x, t = threadIdx.x;
    const size_t base = (size_t)r * Cc;
    const float v0 = ea[base + t] + eb[base + t];
    const float v1 = ea[base + t + 256] + eb[base + t + 256];

    red[t] = fmaxf(v0, v1);
    __syncthreads();
    for (int s = 128; s > 0; s >>= 1) {
        if (t < s) red[t] = fmaxf(red[t], red[t + s]);
        __syncthreads();
    }
    const float mx = red[0];
    __syncthreads();
    const float e0 = expf(v0 - mx);
    const float e1 = expf(v1 - mx);
    red[t] = e0 + e1;
    __syncthreads();
    for (int s = 128; s > 0; s >>= 1) {
        if (t < s) red[t] += red[t + s];
        __syncthreads();
    }
    const float inv = 1.0f / red[0];
    attn[base + t]       = bf_rne(e0 * inv);
    attn[base + t + 256] = bf_rne(e1 * inv);
}

// ---------------------------------------------------------------------------
// pv: out[b][c*HW+n] = aw * sum_d attn[c][d] v[n][d] + x[same flat].
// grid 2048 (1D swizzled); double-buffered gld16, vmcnt(4).
// ---------------------------------------------------------------------------
struct PvBuf { short Ah[128][32]; short Bh[128][32]; };  // 16 KB

__global__ __launch_bounds__(256, 4)
void pv_k(const unsigned short* __restrict__ attn, const unsigned short* __restrict__ v,
          const float* __restrict__ x, const float* __restrict__ aw,
          float* __restrict__ out)
{
    __shared__ PvBuf pbuf[2];   // 32 KB
    const int t = threadIdx.x;
    const int wg = (blockIdx.x & 7) * 256 + (blockIdx.x >> 3);
    const int m0 = (wg & 31) * 128;
    const int c0 = ((wg >> 5) & 3) * 128;
    const int b  = wg >> 7;
    const int lane = t & 63, wave = t >> 6, wr = wave >> 1, wc = wave & 1;
    const int row0 = t >> 2;
    const int qlog = (t & 3) ^ ((t >> 3) & 3);

    f32x4 acc[4][4] = {};
    const size_t ab = (size_t)b * Cc * Cc;
    const size_t vb = (size_t)b * HW * Cc;

    auto issue = [&](int ks, PvBuf* pb) {   // 4 gld16
        const size_t db = (size_t)ks * 32 + qlog * 8;
        gld16(attn + ab + (size_t)(c0 + row0)      * Cc + db, (short*)pb->Ah + t * 8);
        gld16(attn + ab + (size_t)(c0 + row0 + 64) * Cc + db, (short*)pb->Ah + t * 8 + 2048);
        gld16(v + vb + (size_t)(m0 + row0)      * Cc + db, (short*)pb->Bh + t * 8);
        gld16(v + vb + (size_t)(m0 + row0 + 64) * Cc + db, (short*)pb->Bh + t * 8 + 2048);
    };
    auto compute = [&](PvBuf* pb) {
        short8 ah[4];
        const int kq = lane >> 4;
        #pragma unroll
        for (int i = 0; i < 4; ++i)
            ah[i] = *(const short8*)((const short*)pb->Ah + swz8(wr * 64 + i * 16 + (lane & 15), kq));
        __builtin_amdgcn_s_setprio(1);
        #pragma unroll
        for (int j = 0; j < 4; ++j) {
            short8 bh = *(const short8*)((const short*)pb->Bh + swz8(wc * 64 + j * 16 + (lane & 15), kq));
            #pragma unroll
            for (int i = 0; i < 4; ++i)
                acc[i][j] = __builtin_amdgcn_mfma_f32_16x16x32_bf16(ah[i], bh, acc[i][j], 0, 0, 0);
        }
        __builtin_amdgcn_s_setprio(0);
    };

    issue(0, &pbuf[0]);
    for (int ks = 0; ks < 15; ++ks) {
        issue(ks + 1, &pbuf[(ks & 1) ^ 1]);
        __builtin_amdgcn_sched_barrier(0);
        asm volatile("s_waitcnt vmcnt(4)" ::: "memory");
        __builtin_amdgcn_sched_barrier(0);
        __builtin_amdgcn_s_barrier();
        compute(&pbuf[ks & 1]);
        __builtin_amdgcn_s_barrier();
    }
    __builtin_amdgcn_sched_barrier(0);
    asm volatile("s_waitcnt vmcnt(0)" ::: "memory");
    __builtin_amdgcn_sched_barrier(0);
    __builtin_amdgcn_s_barrier();
    compute(&pbuf[1]);

    const float a_w = aw[0];
    #pragma unroll
    for (int i = 0; i < 4; ++i)
        #pragma unroll
        for (int r = 0; r < 4; ++r) {
            const int c = c0 + wr * 64 + i * 16 + (lane >> 4) * 4 + r;
            #pragma unroll
            for (int j = 0; j < 4; ++j) {
                const int n = m0 + wc * 64 + j * 16 + (lane & 15);
                const size_t idx = (size_t)b * ((size_t)Cc * HW) + (size_t)c * HW + n;
                out[idx] = fmaf(a_w, acc[i][j][r], x[idx]);
            }
        }
}

// ---------------------------------------------------------------------------
extern "C" void kernel_launch(void* const* d_in, const int* in_sizes, int n_in,
                              void* d_out, int out_size, void* d_ws, size_t ws_size,
                              hipStream_t stream)
{
    (void)in_sizes; (void)n_in; (void)out_size; (void)ws_size;
    const float* x   = (const float*)d_in[0];
    const float* Wq  = (const float*)d_in[1];
    const float* bq  = (const float*)d_in[2];
    const float* Wk  = (const float*)d_in[3];
    const float* bk  = (const float*)d_in[4];
    const float* Wv  = (const float*)d_in[5];
    const float* bvv = (const float*)d_in[6];
    const float* qg  = (const float*)d_in[7];
    const float* qbt = (const float*)d_in[8];
    const float* qm  = (const float*)d_in[9];
    const float* qv  = (const float*)d_in[10];
    const float* kg  = (const float*)d_in[11];
    const float* kbt = (const float*)d_in[12];
    const float* km  = (const float*)d_in[13];
    const float* kv  = (const float*)d_in[14];
    const float* vg  = (const float*)d_in[15];
    const float* vbt = (const float*)d_in[16];
    const float* vm  = (const float*)d_in[17];
    const float* vvr = (const float*)d_in[18];
    const float* aw  = (const float*)d_in[19];
    float* out = (float*)d_out;

    // Workspace map (peak 363,855,872 B < round-1-proven 419,430,400):
    //  [0,28.3M):    wq_h|wq_l|wk_h|wk_l|wv_h|wv_l
    //  [28.3,162.5M): q_h|q_l   -> v_b after energy (q dead)
    //  [162.5,296.7M): k_h|k_l  (dead after energy)
    //  [296.7,330.3M): e_a|e_b ; [330.3,338.7M): attn (bf16)
    char* w = (char*)d_ws;
    unsigned short* wq_h = (unsigned short*)(w);
    unsigned short* wq_l = (unsigned short*)(w + 4718592);
    unsigned short* wk_h = (unsigned short*)(w + 9437184);
    unsigned short* wk_l = (unsigned short*)(w + 14155776);
    unsigned short* wv_h = (unsigned short*)(w + 18874368);
    unsigned short* wv_l = (unsigned short*)(w + 23592960);
    unsigned short* q_h  = (unsigned short*)(w + 28311552);
    unsigned short* q_l  = (unsigned short*)(w + 95420416);
    unsigned short* k_h  = (unsigned short*)(w + 162529280);
    unsigned short* k_l  = (unsigned short*)(w + 229638144);
    float*          e_a  = (float*)(w + 296747008);
    float*          e_b  = (float*)(w + 313524224);
    unsigned short* attn = (unsigned short*)(w + 330301440);
    unsigned short* v_b  = q_h;   // alias: conv_v runs after energy (q dead)

    const dim3 blk(256);
    const dim3 wgrid(16, 16, 9);

    wsplit_k<<<wgrid, blk, 0, stream>>>(Wq, wq_h, wq_l);
    wsplit_k<<<wgrid, blk, 0, stream>>>(Wk, wk_h, wk_l);
    wsplit_k<<<wgrid, blk, 0, stream>>>(Wv, wv_h, wv_l);

    conv_qk_k<<<dim3(2048), blk, 0, stream>>>(x, wq_h, wq_l, wk_h, wk_l,
                                              bq, qg, qbt, qm, qv,
                                              bk, kg, kbt, km, kv,
                                              q_h, q_l, k_h, k_l);

    energy_k<<<dim3(512), blk, 0, stream>>>(q_h, q_l, k_h, k_l, e_a, e_b);
    softmax_k<<<dim3(8192), blk, 0, stream>>>(e_a, e_b, attn);

    conv_v_k<<<dim3(2048), blk, 0, stream>>>(x, wv_h, bvv, vg, vbt, vm, vvr, v_b);

    pv_k<<<dim3(2048), blk, 0, stream>>>(attn, v_b, x, aw, out);
}

// Round 7
// 2149.543 us; speedup vs baseline: 1.1568x; 1.1568x over previous
//
#include <hip/hip_runtime.h>
#include <cstdint>

constexpr int Hh = 64, Wd = 64, Cc = 512;
constexpr int HW = 4096;
#define BN_EPS 1e-3f

typedef __attribute__((ext_vector_type(8))) short short8;
typedef __attribute__((ext_vector_type(4))) float f32x4;

__device__ __forceinline__ void gld16(const void* g, void* l) {
    __builtin_amdgcn_global_load_lds((const __attribute__((address_space(1))) void*)g,
                                     (__attribute__((address_space(3))) void*)l, 16, 0, 0);
}
__device__ __forceinline__ unsigned short bf_rne(float f) {
    uint32_t u = __float_as_uint(f);
    return (unsigned short)((u + 0x7fffu + ((u >> 16) & 1u)) >> 16);
}
// RNE split: f ~= hi + lo with hi = RNE_bf16(f), lo = RNE_bf16(f - hi).
// (weights + epilogue; x staging uses the fast perm-based trunc split)
__device__ __forceinline__ void split2(float f, unsigned short& hi, unsigned short& lo) {
    hi = bf_rne(f);
    float hf = __uint_as_float((uint32_t)hi << 16);
    lo = bf_rne(f - hf);
}
// short-index of logical [r][q*8] in a [128 rows][4 slots of 16B] plane,
// slot-swizzled: phys_slot = q ^ ((r>>1)&3)  -> conflict-free ds_read_b128
__device__ __forceinline__ int swz8(int r, int q) {
    return r * 32 + (((q ^ (r >> 1)) & 3) << 3);
}
__device__ __forceinline__ short8 msel(bool v, short8 a) {
    short m = v ? (short)-1 : (short)0;
    short8 mv = {m, m, m, m, m, m, m, m};
    return a & mv;
}

// ---------------------------------------------------------------------------
// W [tap][cin][cout] fp32 -> Wt_hi/lo [cout][tap*512+cin] bf16. grid (16,16,9)
// ---------------------------------------------------------------------------
__global__ __launch_bounds__(256)
void wsplit_k(const float* __restrict__ W, unsigned short* __restrict__ wh,
              unsigned short* __restrict__ wl)
{
    __shared__ float T[32][33];
    const int tap = blockIdx.z, ci0 = blockIdx.x * 32, co0 = blockIdx.y * 32;
    const int t = threadIdx.x;
    const int ci = t >> 5, co = t & 31;
    #pragma unroll
    for (int rep = 0; rep < 4; ++rep)
        T[ci + rep * 8][co] = W[(size_t)((tap * Cc) + ci0 + ci + rep * 8) * Cc + co0 + co];
    __syncthreads();
    const int co2 = t >> 5, ci2 = t & 31;
    #pragma unroll
    for (int rep = 0; rep < 4; ++rep) {
        float v = T[ci2][co2 + rep * 8];
        unsigned short h, l; split2(v, h, l);
        size_t addr = (size_t)(co0 + co2 + rep * 8) * 4608 + (size_t)tap * Cc + ci0 + ci2;
        wh[addr] = h; wl[addr] = l;
    }
}

// ---------------------------------------------------------------------------
// FUSED Q+K conv3x3 SAME + BN + ReLU, split-bf16 (3 MFMA products each).
// Round-5 structure; staging split via v_perm trunc pack; 2x-unrolled
// ks-loop ping-pongs xc/xn (no copy). A: dbuf gld16, counted vmcnt(12).
// grid 2048 (1D, XCD-swizzled). Outputs transposed [b][c][n] hi/lo.
// ---------------------------------------------------------------------------
struct QkA { short QH[128][32]; short QL[128][32]; short KH[128][32]; short KL[128][32]; }; // 32 KB
struct QkB { short BH[128][32]; short BL[128][32]; };                                      // 16 KB
struct QkLds { QkA a[2]; QkB b; };                                                         // 80 KB

__global__ __launch_bounds__(256, 2)
void conv_qk_k(const float* __restrict__ x,
               const unsigned short* __restrict__ wqh, const unsigned short* __restrict__ wql,
               const unsigned short* __restrict__ wkh, const unsigned short* __restrict__ wkl,
               const float* __restrict__ bq_, const float* __restrict__ qg_,
               const float* __restrict__ qbt_, const float* __restrict__ qm_,
               const float* __restrict__ qv_,
               const float* __restrict__ bk_, const float* __restrict__ kg_,
               const float* __restrict__ kbt_, const float* __restrict__ km_,
               const float* __restrict__ kv_,
               unsigned short* __restrict__ q_h, unsigned short* __restrict__ q_l,
               unsigned short* __restrict__ k_h, unsigned short* __restrict__ k_l)
{
    __shared__ QkLds lds;
    const int t = threadIdx.x;
    const int wg = (blockIdx.x & 7) * 256 + (blockIdx.x >> 3);   // bijective XCD swizzle
    const int bcout = (wg & 3) * 128;
    const int m0    = ((wg >> 2) & 31) * 128;
    const int b     = wg >> 7;
    const int lane = t & 63, wave = t >> 6;
    const int wr = wave >> 1, wc = wave & 1;

    const int row0 = t >> 2;                      // 0..63
    const int slot = t & 3;                       // logical 16B slot (B staging)
    const int qlog = slot ^ ((t >> 3) & 3);       // pre-swizzled source slot (A gld16)

    const int m_r0 = m0 + row0, m_r1 = m_r0 + 64;
    const int h0 = m_r0 >> 6, w0 = m_r0 & 63;
    const int h1 = m_r1 >> 6, w1 = m_r1 & 63;
    const float* xb = x + (size_t)b * HW * Cc;

    const int dsb0 = swz8(row0, slot);            // static ds_write targets
    const int dsb1 = swz8(row0 + 64, slot);

    f32x4 accq[4][4] = {};
    f32x4 acck[4][4] = {};
    float xc[16], xn[16];
    bool vc0, vc1, vn0, vn1;

    // fp32 x tile rows into regs; clamp addr in-bounds, defer boundary masking
    auto loadx = [&](int ks, float* xd, bool& v0, bool& v1) {
        const int tap = ks >> 4;
        const int kk  = ((ks & 15) << 5) + slot * 8;
        const int dy = tap / 3 - 1, dx = tap % 3 - 1;
        {
            const int hp = h0 + dy, wp = w0 + dx;
            v0 = ((unsigned)hp < 64u) & ((unsigned)wp < 64u);
            const int hc = min(max(hp, 0), 63), wcl = min(max(wp, 0), 63);
            const float* p = xb + ((size_t)(hc * Wd + wcl)) * Cc + kk;
            float4 u0 = *(const float4*)p;
            float4 u1 = *(const float4*)(p + 4);
            xd[0] = u0.x; xd[1] = u0.y; xd[2] = u0.z; xd[3] = u0.w;
            xd[4] = u1.x; xd[5] = u1.y; xd[6] = u1.z; xd[7] = u1.w;
        }
        {
            const int hp = h1 + dy, wp = w1 + dx;
            v1 = ((unsigned)hp < 64u) & ((unsigned)wp < 64u);
            const int hc = min(max(hp, 0), 63), wcl = min(max(wp, 0), 63);
            const float* p = xb + ((size_t)(hc * Wd + wcl)) * Cc + kk;
            float4 u0 = *(const float4*)p;
            float4 u1 = *(const float4*)(p + 4);
            xd[8]  = u0.x; xd[9]  = u0.y; xd[10] = u0.z; xd[11] = u0.w;
            xd[12] = u1.x; xd[13] = u1.y; xd[14] = u1.z; xd[15] = u1.w;
        }
    };

    auto issueA = [&](int ks, QkA* ab) {   // 8 gld16, pre-swizzled source col
        const int tap = ks >> 4;
        const size_t kb = (size_t)tap * Cc + ((ks & 15) << 5) + qlog * 8;
        const size_t r0 = (size_t)(bcout + row0) * 4608 + kb;
        const size_t r1 = (size_t)(bcout + row0 + 64) * 4608 + kb;
        gld16(wqh + r0, (short*)ab->QH + t * 8);
        gld16(wqh + r1, (short*)ab->QH + t * 8 + 2048);
        gld16(wql + r0, (short*)ab->QL + t * 8);
        gld16(wql + r1, (short*)ab->QL + t * 8 + 2048);
        gld16(wkh + r0, (short*)ab->KH + t * 8);
        gld16(wkh + r1, (short*)ab->KH + t * 8 + 2048);
        gld16(wkl + r0, (short*)ab->KL + t * 8);
        gld16(wkl + r1, (short*)ab->KL + t * 8 + 2048);
    };

    // perm-based trunc split + mask + swizzled ds_write (hot path):
    // hi = top16(f) packed pairwise; lo = top16(f - hi) (residual, trunc).
    auto stageB = [&](const float* xv, bool v0, bool v1) {
        const uint32_t* f = (const uint32_t*)xv;
        uint32_t hi[4], lo[4];
        const uint32_t mk0 = v0 ? 0xffffffffu : 0u;
        #pragma unroll
        for (int p2 = 0; p2 < 4; ++p2) {
            const uint32_t f0 = f[2 * p2], f1 = f[2 * p2 + 1];
            hi[p2] = __builtin_amdgcn_perm(f1, f0, 0x07060302u) & mk0;
            const float d0 = __uint_as_float(f0) - __uint_as_float(f0 & 0xffff0000u);
            const float d1 = __uint_as_float(f1) - __uint_as_float(f1 & 0xffff0000u);
            lo[p2] = __builtin_amdgcn_perm(__float_as_uint(d1), __float_as_uint(d0),
                                           0x07060302u) & mk0;
        }
        *(uint4*)((short*)lds.b.BH + dsb0) = *(uint4*)hi;
        *(uint4*)((short*)lds.b.BL + dsb0) = *(uint4*)lo;
        const uint32_t mk1 = v1 ? 0xffffffffu : 0u;
        #pragma unroll
        for (int p2 = 0; p2 < 4; ++p2) {
            const uint32_t f0 = f[8 + 2 * p2], f1 = f[8 + 2 * p2 + 1];
            hi[p2] = __builtin_amdgcn_perm(f1, f0, 0x07060302u) & mk1;
            const float d0 = __uint_as_float(f0) - __uint_as_float(f0 & 0xffff0000u);
            const float d1 = __uint_as_float(f1) - __uint_as_float(f1 & 0xffff0000u);
            lo[p2] = __builtin_amdgcn_perm(__float_as_uint(d1), __float_as_uint(d0),
                                           0x07060302u) & mk1;
        }
        *(uint4*)((short*)lds.b.BH + dsb1) = *(uint4*)hi;
        *(uint4*)((short*)lds.b.BL + dsb1) = *(uint4*)lo;
    };

    auto compute = [&](QkA* ab) {
        const int kq = lane >> 4;
        short8 ah[4], al[4];
        // ---- phase Q ----
        #pragma unroll
        for (int i = 0; i < 4; ++i) {
            const int r = wr * 64 + i * 16 + (lane & 15);
            ah[i] = *(const short8*)((const short*)ab->QH + swz8(r, kq));
            al[i] = *(const short8*)((const short*)ab->QL + swz8(r, kq));
        }
        __builtin_amdgcn_s_setprio(1);
        #pragma unroll
        for (int j = 0; j < 4; ++j) {
            const int r = wc * 64 + j * 16 + (lane & 15);
            short8 bh = *(const short8*)((const short*)lds.b.BH + swz8(r, kq));
            short8 bl = *(const short8*)((const short*)lds.b.BL + swz8(r, kq));
            #pragma unroll
            for (int i = 0; i < 4; ++i) {
                accq[i][j] = __builtin_amdgcn_mfma_f32_16x16x32_bf16(ah[i], bh, accq[i][j], 0, 0, 0);
                accq[i][j] = __builtin_amdgcn_mfma_f32_16x16x32_bf16(ah[i], bl, accq[i][j], 0, 0, 0);
                accq[i][j] = __builtin_amdgcn_mfma_f32_16x16x32_bf16(al[i], bh, accq[i][j], 0, 0, 0);
            }
        }
        __builtin_amdgcn_s_setprio(0);
        // ---- phase K ----
        #pragma unroll
        for (int i = 0; i < 4; ++i) {
            const int r = wr * 64 + i * 16 + (lane & 15);
            ah[i] = *(const short8*)((const short*)ab->KH + swz8(r, kq));
            al[i] = *(const short8*)((const short*)ab->KL + swz8(r, kq));
        }
        __builtin_amdgcn_s_setprio(1);
        #pragma unroll
        for (int j = 0; j < 4; ++j) {
            const int r = wc * 64 + j * 16 + (lane & 15);
            short8 bh = *(const short8*)((const short*)lds.b.BH + swz8(r, kq));
            short8 bl = *(const short8*)((const short*)lds.b.BL + swz8(r, kq));
            #pragma unroll
            for (int i = 0; i < 4; ++i) {
                acck[i][j] = __builtin_amdgcn_mfma_f32_16x16x32_bf16(ah[i], bh, acck[i][j], 0, 0, 0);
                acck[i][j] = __builtin_amdgcn_mfma_f32_16x16x32_bf16(ah[i], bl, acck[i][j], 0, 0, 0);
                acck[i][j] = __builtin_amdgcn_mfma_f32_16x16x32_bf16(al[i], bh, acck[i][j], 0, 0, 0);
            }
        }
        __builtin_amdgcn_s_setprio(0);
    };

    loadx(0, xc, vc0, vc1);
    issueA(0, &lds.a[0]);

    // 2x-unrolled main loop: steps (ks, ks+1) for ks = 0,2,...,140  (142 steps)
    for (int ks = 0; ks < 142; ks += 2) {
        // --- even step ks: stage xc, compute buf0 ---
        loadx(ks + 1, xn, vn0, vn1);
        issueA(ks + 1, &lds.a[1]);
        stageB(xc, vc0, vc1);
        __builtin_amdgcn_sched_barrier(0);
        asm volatile("s_waitcnt vmcnt(12) lgkmcnt(0)" ::: "memory");
        __builtin_amdgcn_sched_barrier(0);
        __builtin_amdgcn_s_barrier();
        compute(&lds.a[0]);
        __builtin_amdgcn_s_barrier();
        // --- odd step ks+1: stage xn, compute buf1 ---
        loadx(ks + 2, xc, vc0, vc1);
        issueA(ks + 2, &lds.a[0]);
        stageB(xn, vn0, vn1);
        __builtin_amdgcn_sched_barrier(0);
        asm volatile("s_waitcnt vmcnt(12) lgkmcnt(0)" ::: "memory");
        __builtin_amdgcn_sched_barrier(0);
        __builtin_amdgcn_s_barrier();
        compute(&lds.a[1]);
        __builtin_amdgcn_s_barrier();
    }
    // step 142 (even): issues A(143) -> buf1
    loadx(143, xn, vn0, vn1);
    issueA(143, &lds.a[1]);
    stageB(xc, vc0, vc1);
    __builtin_amdgcn_sched_barrier(0);
    asm volatile("s_waitcnt vmcnt(12) lgkmcnt(0)" ::: "memory");
    __builtin_amdgcn_sched_barrier(0);
    __builtin_amdgcn_s_barrier();
    compute(&lds.a[0]);
    __builtin_amdgcn_s_barrier();
    // tail step 143
    stageB(xn, vn0, vn1);
    __builtin_amdgcn_sched_barrier(0);
    asm volatile("s_waitcnt vmcnt(0) lgkmcnt(0)" ::: "memory");
    __builtin_amdgcn_sched_barrier(0);
    __builtin_amdgcn_s_barrier();
    compute(&lds.a[1]);

    // epilogue: folded BN + ReLU for q and k; write transposed hi/lo planes
    #pragma unroll
    for (int i = 0; i < 4; ++i) {
        #pragma unroll
        for (int r = 0; r < 4; ++r) {
            const int co = bcout + wr * 64 + i * 16 + (lane >> 4) * 4 + r;
            const float scq = qg_[co] * rsqrtf(qv_[co] + BN_EPS);
            const float tbq = (bq_[co] - qm_[co]) * scq + qbt_[co];
            const float sck = kg_[co] * rsqrtf(kv_[co] + BN_EPS);
            const float tbk = (bk_[co] - km_[co]) * sck + kbt_[co];
            const size_t rowb = ((size_t)(b * Cc + co)) * HW;
            #pragma unroll
            for (int j = 0; j < 4; ++j) {
                const int n = m0 + wc * 64 + j * 16 + (lane & 15);
                const float yq = fmaxf(fmaf(accq[i][j][r], scq, tbq), 0.f);
                const float yk = fmaxf(fmaf(acck[i][j][r], sck, tbk), 0.f);
                unsigned short h, l;
                split2(yq, h, l); q_h[rowb + n] = h; q_l[rowb + n] = l;
                split2(yk, h, l); k_h[rowb + n] = h; k_l[rowb + n] = l;
            }
        }
    }
}

// ---------------------------------------------------------------------------
// V conv3x3 SAME + BN + ReLU, PLAIN bf16 (1 MFMA product; wv_h/x are RNE).
// Stores v [b][n][c] bf16 via LDS transpose. grid 2048 (1D swizzled).
// ---------------------------------------------------------------------------
union VLds {
    struct { short A0[2][128][32]; short BH[128][32]; } s;  // 24 KB
    short T[128][136];                                      // 34 KB
};

__global__ __launch_bounds__(256, 4)
void conv_v_k(const float* __restrict__ x, const unsigned short* __restrict__ wvh,
              const float* __restrict__ bv_, const float* __restrict__ vg_,
              const float* __restrict__ vbt_, const float* __restrict__ vm_,
              const float* __restrict__ vv_,
              unsigned short* __restrict__ vout)
{
    __shared__ VLds lds;
    const int t = threadIdx.x;
    const int wg = (blockIdx.x & 7) * 256 + (blockIdx.x >> 3);
    const int bcout = (wg & 3) * 128;
    const int m0    = ((wg >> 2) & 31) * 128;
    const int b     = wg >> 7;
    const int lane = t & 63, wave = t >> 6;
    const int wr = wave >> 1, wc = wave & 1;

    const int row0 = t >> 2;
    const int slot = t & 3;
    const int qlog = slot ^ ((t >> 3) & 3);

    const int m_r0 = m0 + row0, m_r1 = m_r0 + 64;
    const int h0 = m_r0 >> 6, w0 = m_r0 & 63;
    const int h1 = m_r1 >> 6, w1 = m_r1 & 63;
    const float* xb = x + (size_t)b * HW * Cc;

    f32x4 acc[4][4] = {};
    float xc[16], xn[16];
    bool vc0, vc1, vn0, vn1;

    auto loadx = [&](int ks, float* xd, bool& v0, bool& v1) {
        const int tap = ks >> 4;
        const int kk  = ((ks & 15) << 5) + slot * 8;
        const int dy = tap / 3 - 1, dx = tap % 3 - 1;
        {
            const int hp = h0 + dy, wp = w0 + dx;
            v0 = ((unsigned)hp < 64u) & ((unsigned)wp < 64u);
            const int hc = min(max(hp, 0), 63), wcl = min(max(wp, 0), 63);
            const float* p = xb + ((size_t)(hc * Wd + wcl)) * Cc + kk;
            float4 u0 = *(const float4*)p;
            float4 u1 = *(const float4*)(p + 4);
            xd[0] = u0.x; xd[1] = u0.y; xd[2] = u0.z; xd[3] = u0.w;
            xd[4] = u1.x; xd[5] = u1.y; xd[6] = u1.z; xd[7] = u1.w;
        }
        {
            const int hp = h1 + dy, wp = w1 + dx;
            v1 = ((unsigned)hp < 64u) & ((unsigned)wp < 64u);
            const int hc = min(max(hp, 0), 63), wcl = min(max(wp, 0), 63);
            const float* p = xb + ((size_t)(hc * Wd + wcl)) * Cc + kk;
            float4 u0 = *(const float4*)p;
            float4 u1 = *(const float4*)(p + 4);
            xd[8]  = u0.x; xd[9]  = u0.y; xd[10] = u0.z; xd[11] = u0.w;
            xd[12] = u1.x; xd[13] = u1.y; xd[14] = u1.z; xd[15] = u1.w;
        }
    };
    auto issueA = [&](int ks, int buf) {   // 2 gld16
        const int tap = ks >> 4;
        const size_t kb = (size_t)tap * Cc + ((ks & 15) << 5) + qlog * 8;
        gld16(wvh + (size_t)(bcout + row0)      * 4608 + kb, (short*)lds.s.A0[buf] + t * 8);
        gld16(wvh + (size_t)(bcout + row0 + 64) * 4608 + kb, (short*)lds.s.A0[buf] + t * 8 + 2048);
    };
    auto writeB = [&]() {   // RNE round, mask, swizzled ds_write (hi only)
        short8 hv;
        #pragma unroll
        for (int q2 = 0; q2 < 8; ++q2) hv[q2] = (short)bf_rne(xc[q2]);
        *(short8*)((short*)lds.s.BH + swz8(row0, slot)) = msel(vc0, hv);
        #pragma unroll
        for (int q2 = 0; q2 < 8; ++q2) hv[q2] = (short)bf_rne(xc[8 + q2]);
        *(short8*)((short*)lds.s.BH + swz8(row0 + 64, slot)) = msel(vc1, hv);
    };
    auto compute = [&](int buf) {
        const int kq = lane >> 4;
        short8 ah[4];
        #pragma unroll
        for (int i = 0; i < 4; ++i)
            ah[i] = *(const short8*)((const short*)lds.s.A0[buf] + swz8(wr * 64 + i * 16 + (lane & 15), kq));
        __builtin_amdgcn_s_setprio(1);
        #pragma unroll
        for (int j = 0; j < 4; ++j) {
            short8 bh = *(const short8*)((const short*)lds.s.BH + swz8(wc * 64 + j * 16 + (lane & 15), kq));
            #pragma unroll
            for (int i = 0; i < 4; ++i)
                acc[i][j] = __builtin_amdgcn_mfma_f32_16x16x32_bf16(ah[i], bh, acc[i][j], 0, 0, 0);
        }
        __builtin_amdgcn_s_setprio(0);
    };

    loadx(0, xc, vc0, vc1);
    issueA(0, 0);

    for (int ks = 0; ks < 143; ++ks) {
        loadx(ks + 1, xn, vn0, vn1);      // 4 vmem
        issueA(ks + 1, (ks & 1) ^ 1);     // 2 gld16
        writeB();
        __builtin_amdgcn_sched_barrier(0);
        asm volatile("s_waitcnt vmcnt(6) lgkmcnt(0)" ::: "memory");  // A(ks) landed
        __builtin_amdgcn_sched_barrier(0);
        __builtin_amdgcn_s_barrier();
        compute(ks & 1);
        __builtin_amdgcn_s_barrier();
        #pragma unroll
        for (int q2 = 0; q2 < 16; ++q2) xc[q2] = xn[q2];
        vc0 = vn0; vc1 = vn1;
    }
    writeB();
    __builtin_amdgcn_sched_barrier(0);
    asm volatile("s_waitcnt vmcnt(0) lgkmcnt(0)" ::: "memory");
    __builtin_amdgcn_sched_barrier(0);
    __builtin_amdgcn_s_barrier();
    compute(1);

    // epilogue: BN+ReLU, transpose to [n][c] through LDS
    __syncthreads();
    #pragma unroll
    for (int i = 0; i < 4; ++i) {
        #pragma unroll
        for (int r = 0; r < 4; ++r) {
            const int cl = wr * 64 + i * 16 + (lane >> 4) * 4 + r;
            const int co = bcout + cl;
            const float sc = vg_[co] * rsqrtf(vv_[co] + BN_EPS);
            const float tb = (bv_[co] - vm_[co]) * sc + vbt_[co];
            #pragma unroll
            for (int j = 0; j < 4; ++j) {
                const int nl = wc * 64 + j * 16 + (lane & 15);
                const float y = fmaxf(fmaf(acc[i][j][r], sc, tb), 0.f);
                lds.T[nl][cl] = (short)bf_rne(y);
            }
        }
    }
    __syncthreads();
    #pragma unroll
    for (int rep = 0; rep < 4; ++rep) {
        const int nl = (t >> 3) + rep * 32;
        const int c0l = (t & 7) * 16;
        short8 v0 = *(const short8*)&lds.T[nl][c0l];
        short8 v1 = *(const short8*)&lds.T[nl][c0l + 8];
        const size_t base = ((size_t)(b * HW + m0 + nl)) * Cc + bcout + c0l;
        *(short8*)&vout[base] = v0;
        *(short8*)&vout[base + 8] = v1;
    }
}

// ---------------------------------------------------------------------------
// energy[b][c][d] = sum_n q_t[c][n] k_t[d][n], split-bf16, split-K=2.
// grid 512 (1D swizzled): z = b*2 + half -> e_a / e_b partials.
// ---------------------------------------------------------------------------
struct EBuf { short Ah[128][32]; short Al[128][32]; short Bh[128][32]; short Bl[128][32]; }; // 32 KB

__global__ __launch_bounds__(256, 2)
void energy_k(const unsigned short* __restrict__ qh, const unsigned short* __restrict__ ql,
              const unsigned short* __restrict__ kh, const unsigned short* __restrict__ kl,
              float* __restrict__ ea, float* __restrict__ eb)
{
    __shared__ EBuf ebuf[2];   // 64 KB
    const int t = threadIdx.x;
    const int wg = (blockIdx.x & 7) * 64 + (blockIdx.x >> 3);
    const int d0 = (wg & 3) * 128;
    const int c0 = ((wg >> 2) & 3) * 128;
    const int z  = wg >> 4;
    const int b  = z >> 1;
    const int nb0 = (z & 1) * 2048;
    float* __restrict__ eo = (z & 1) ? eb : ea;
    const int lane = t & 63, wave = t >> 6, wr = wave >> 1, wc = wave & 1;
    const int row0 = t >> 2;
    const int qlog = (t & 3) ^ ((t >> 3) & 3);

    const size_t qb = (size_t)b * Cc * HW;
    f32x4 acc[4][4] = {};

    auto issue = [&](int ks, EBuf* e8) {   // 8 gld16
        const size_t nb = nb0 + (size_t)ks * 32 + qlog * 8;
        gld16(qh + qb + (size_t)(c0 + row0)      * HW + nb, (short*)e8->Ah + t * 8);
        gld16(qh + qb + (size_t)(c0 + row0 + 64) * HW + nb, (short*)e8->Ah + t * 8 + 2048);
        gld16(ql + qb + (size_t)(c0 + row0)      * HW + nb, (short*)e8->Al + t * 8);
        gld16(ql + qb + (size_t)(c0 + row0 + 64) * HW + nb, (short*)e8->Al + t * 8 + 2048);
        gld16(kh + qb + (size_t)(d0 + row0)      * HW + nb, (short*)e8->Bh + t * 8);
        gld16(kh + qb + (size_t)(d0 + row0 + 64) * HW + nb, (short*)e8->Bh + t * 8 + 2048);
        gld16(kl + qb + (size_t)(d0 + row0)      * HW + nb, (short*)e8->Bl + t * 8);
        gld16(kl + qb + (size_t)(d0 + row0 + 64) * HW + nb, (short*)e8->Bl + t * 8 + 2048);
    };
    auto compute = [&](EBuf* e8) {
        short8 ah[4], al[4];
        const int kq = lane >> 4;
        #pragma unroll
        for (int i = 0; i < 4; ++i) {
            const int r = wr * 64 + i * 16 + (lane & 15);
            ah[i] = *(const short8*)((const short*)e8->Ah + swz8(r, kq));
            al[i] = *(const short8*)((const short*)e8->Al + swz8(r, kq));
        }
        __builtin_amdgcn_s_setprio(1);
        #pragma unroll
        for (int j = 0; j < 4; ++j) {
            const int r = wc * 64 + j * 16 + (lane & 15);
            short8 bh = *(const short8*)((const short*)e8->Bh + swz8(r, kq));
            short8 bl = *(const short8*)((const short*)e8->Bl + swz8(r, kq));
            #pragma unroll
            for (int i = 0; i < 4; ++i) {
                acc[i][j] = __builtin_amdgcn_mfma_f32_16x16x32_bf16(ah[i], bh, acc[i][j], 0, 0, 0);
                acc[i][j] = __builtin_amdgcn_mfma_f32_16x16x32_bf16(ah[i], bl, acc[i][j], 0, 0, 0);
                acc[i][j] = __builtin_amdgcn_mfma_f32_16x16x32_bf16(al[i], bh, acc[i][j], 0, 0, 0);
            }
        }
        __builtin_amdgcn_s_setprio(0);
    };

    issue(0, &ebuf[0]);
    for (int ks = 0; ks < 63; ++ks) {
        issue(ks + 1, &ebuf[(ks & 1) ^ 1]);
        __builtin_amdgcn_sched_barrier(0);
        asm volatile("s_waitcnt vmcnt(8)" ::: "memory");
        __builtin_amdgcn_sched_barrier(0);
        __builtin_amdgcn_s_barrier();
        compute(&ebuf[ks & 1]);
        __builtin_amdgcn_s_barrier();
    }
    __builtin_amdgcn_sched_barrier(0);
    asm volatile("s_waitcnt vmcnt(0)" ::: "memory");
    __builtin_amdgcn_sched_barrier(0);
    __builtin_amdgcn_s_barrier();
    compute(&ebuf[1]);

    #pragma unroll
    for (int i = 0; i < 4; ++i)
        #pragma unroll
        for (int r = 0; r < 4; ++r) {
            const int c = c0 + wr * 64 + i * 16 + (lane >> 4) * 4 + r;
            #pragma unroll
            for (int j = 0; j < 4; ++j) {
                const int d = d0 + wc * 64 + j * 16 + (lane & 15);
                eo[((size_t)(b * Cc) + c) * Cc + d] = acc[i][j][r];
            }
        }
}

// ---------------------------------------------------------------------------
// softmax rows (B*C = 8192), adds split-K partials, writes bf16 attn
// ---------------------------------------------------------------------------
__global__ __launch_bounds__(256)
void softmax_k(const float* __restrict__ ea, const float* __restrict__ eb,
               unsigned short* __restrict__ attn)
{
    __shared__ float red[256];
    const int r = blockIdx.x, t = threadIdx.x;
    const size_t base = (size_t)r * Cc;
    const float v0 = ea[base + t] + eb[base + t];
    const float v1 = ea[base + t + 256] + eb[base + t + 256];

    red[t] = fmaxf(v0, v1);
    __syncthreads();
    for (int s = 128; s > 0; s >>= 1) {
        if (t < s) red[t] = fmaxf(red[t], red[t + s]);
        __syncthreads();
    }
    const float mx = red[0];
    __syncthreads();
    const float e0 = expf(v0 - mx);
    const float e1 = expf(v1 - mx);
    red[t] = e0 + e1;
    __syncthreads();
    for (int s = 128; s > 0; s >>= 1) {
        if (t < s) red[t] += red[t + s];
        __syncthreads();
    }
    const float inv = 1.0f / red[0];
    attn[base + t]       = bf_rne(e0 * inv);
    attn[base + t + 256] = bf_rne(e1 * inv);
}

// ---------------------------------------------------------------------------
// pv: out[b][c*HW+n] = aw * sum_d attn[c][d] v[n][d] + x[same flat].
// grid 2048 (1D swizzled); double-buffered gld16, vmcnt(4).
// ---------------------------------------------------------------------------
struct PvBuf { short Ah[128][32]; short Bh[128][32]; };  // 16 KB

__global__ __launch_bounds__(256, 4)
void pv_k(const unsigned short* __restrict__ attn, const unsigned short* __restrict__ v,
          const float* __restrict__ x, const float* __restrict__ aw,
          float* __restrict__ out)
{
    __shared__ PvBuf pbuf[2];   // 32 KB
    const int t = threadIdx.x;
    const int wg = (blockIdx.x & 7) * 256 + (blockIdx.x >> 3);
    const int m0 = (wg & 31) * 128;
    const int c0 = ((wg >> 5) & 3) * 128;
    const int b  = wg >> 7;
    const int lane = t & 63, wave = t >> 6, wr = wave >> 1, wc = wave & 1;
    const int row0 = t >> 2;
    const int qlog = (t & 3) ^ ((t >> 3) & 3);

    f32x4 acc[4][4] = {};
    const size_t ab = (size_t)b * Cc * Cc;
    const size_t vb = (size_t)b * HW * Cc;

    auto issue = [&](int ks, PvBuf* pb) {   // 4 gld16
        const size_t db = (size_t)ks * 32 + qlog * 8;
        gld16(attn + ab + (size_t)(c0 + row0)      * Cc + db, (short*)pb->Ah + t * 8);
        gld16(attn + ab + (size_t)(c0 + row0 + 64) * Cc + db, (short*)pb->Ah + t * 8 + 2048);
        gld16(v + vb + (size_t)(m0 + row0)      * Cc + db, (short*)pb->Bh + t * 8);
        gld16(v + vb + (size_t)(m0 + row0 + 64) * Cc + db, (short*)pb->Bh + t * 8 + 2048);
    };
    auto compute = [&](PvBuf* pb) {
        short8 ah[4];
        const int kq = lane >> 4;
        #pragma unroll
        for (int i = 0; i < 4; ++i)
            ah[i] = *(const short8*)((const short*)pb->Ah + swz8(wr * 64 + i * 16 + (lane & 15), kq));
        __builtin_amdgcn_s_setprio(1);
        #pragma unroll
        for (int j = 0; j < 4; ++j) {
            short8 bh = *(const short8*)((const short*)pb->Bh + swz8(wc * 64 + j * 16 + (lane & 15), kq));
            #pragma unroll
            for (int i = 0; i < 4; ++i)
                acc[i][j] = __builtin_amdgcn_mfma_f32_16x16x32_bf16(ah[i], bh, acc[i][j], 0, 0, 0);
        }
        __builtin_amdgcn_s_setprio(0);
    };

    issue(0, &pbuf[0]);
    for (int ks = 0; ks < 15; ++ks) {
        issue(ks + 1, &pbuf[(ks & 1) ^ 1]);
        __builtin_amdgcn_sched_barrier(0);
        asm volatile("s_waitcnt vmcnt(4)" ::: "memory");
        __builtin_amdgcn_sched_barrier(0);
        __builtin_amdgcn_s_barrier();
        compute(&pbuf[ks & 1]);
        __builtin_amdgcn_s_barrier();
    }
    __builtin_amdgcn_sched_barrier(0);
    asm volatile("s_waitcnt vmcnt(0)" ::: "memory");
    __builtin_amdgcn_sched_barrier(0);
    __builtin_amdgcn_s_barrier();
    compute(&pbuf[1]);

    const float a_w = aw[0];
    #pragma unroll
    for (int i = 0; i < 4; ++i)
        #pragma unroll
        for (int r = 0; r < 4; ++r) {
            const int c = c0 + wr * 64 + i * 16 + (lane >> 4) * 4 + r;
            #pragma unroll
            for (int j = 0; j < 4; ++j) {
                const int n = m0 + wc * 64 + j * 16 + (lane & 15);
                const size_t idx = (size_t)b * ((size_t)Cc * HW) + (size_t)c * HW + n;
                out[idx] = fmaf(a_w, acc[i][j][r], x[idx]);
            }
        }
}

// ---------------------------------------------------------------------------
extern "C" void kernel_launch(void* const* d_in, const int* in_sizes, int n_in,
                              void* d_out, int out_size, void* d_ws, size_t ws_size,
                              hipStream_t stream)
{
    (void)in_sizes; (void)n_in; (void)out_size; (void)ws_size;
    const float* x   = (const float*)d_in[0];
    const float* Wq  = (const float*)d_in[1];
    const float* bq  = (const float*)d_in[2];
    const float* Wk  = (const float*)d_in[3];
    const float* bk  = (const float*)d_in[4];
    const float* Wv  = (const float*)d_in[5];
    const float* bvv = (const float*)d_in[6];
    const float* qg  = (const float*)d_in[7];
    const float* qbt = (const float*)d_in[8];
    const float* qm  = (const float*)d_in[9];
    const float* qv  = (const float*)d_in[10];
    const float* kg  = (const float*)d_in[11];
    const float* kbt = (const float*)d_in[12];
    const float* km  = (const float*)d_in[13];
    const float* kv  = (const float*)d_in[14];
    const float* vg  = (const float*)d_in[15];
    const float* vbt = (const float*)d_in[16];
    const float* vm  = (const float*)d_in[17];
    const float* vvr = (const float*)d_in[18];
    const float* aw  = (const float*)d_in[19];
    float* out = (float*)d_out;

    // Workspace map (peak 363,855,872 B < round-1-proven 419,430,400):
    //  [0,28.3M):    wq_h|wq_l|wk_h|wk_l|wv_h|wv_l
    //  [28.3,162.5M): q_h|q_l   -> v_b after energy (q dead)
    //  [162.5,296.7M): k_h|k_l  (dead after energy)
    //  [296.7,330.3M): e_a|e_b ; [330.3,338.7M): attn (bf16)
    char* w = (char*)d_ws;
    unsigned short* wq_h = (unsigned short*)(w);
    unsigned short* wq_l = (unsigned short*)(w + 4718592);
    unsigned short* wk_h = (unsigned short*)(w + 9437184);
    unsigned short* wk_l = (unsigned short*)(w + 14155776);
    unsigned short* wv_h = (unsigned short*)(w + 18874368);
    unsigned short* wv_l = (unsigned short*)(w + 23592960);
    unsigned short* q_h  = (unsigned short*)(w + 28311552);
    unsigned short* q_l  = (unsigned short*)(w + 95420416);
    unsigned short* k_h  = (unsigned short*)(w + 162529280);
    unsigned short* k_l  = (unsigned short*)(w + 229638144);
    float*          e_a  = (float*)(w + 296747008);
    float*          e_b  = (float*)(w + 313524224);
    unsigned short* attn = (unsigned short*)(w + 330301440);
    unsigned short* v_b  = q_h;   // alias: conv_v runs after energy (q dead)

    const dim3 blk(256);
    const dim3 wgrid(16, 16, 9);

    wsplit_k<<<wgrid, blk, 0, stream>>>(Wq, wq_h, wq_l);
    wsplit_k<<<wgrid, blk, 0, stream>>>(Wk, wk_h, wk_l);
    wsplit_k<<<wgrid, blk, 0, stream>>>(Wv, wv_h, wv_l);

    conv_qk_k<<<dim3(2048), blk, 0, stream>>>(x, wq_h, wq_l, wk_h, wk_l,
                                              bq, qg, qbt, qm, qv,
                                              bk, kg, kbt, km, kv,
                                              q_h, q_l, k_h, k_l);

    energy_k<<<dim3(512), blk, 0, stream>>>(q_h, q_l, k_h, k_l, e_a, e_b);
    softmax_k<<<dim3(8192), blk, 0, stream>>>(e_a, e_b, attn);

    conv_v_k<<<dim3(2048), blk, 0, stream>>>(x, wv_h, bvv, vg, vbt, vm, vvr, v_b);

    pv_k<<<dim3(2048), blk, 0, stream>>>(attn, v_b, x, aw, out);
}